// Round 1
// baseline (293.570 us; speedup 1.0000x reference)
//
#include <hip/hip_runtime.h>
#include <cstdint>
#include <math.h>

// ---------------------------------------------------------------------------
// BigBird attention, MI355X. B=2, S=2048, E=1024, H=16, D=64, BLOCK=64, NB=32.
// Pipeline: fp32->bf16 cvt -> fused QKV GEMM (bf16 MFMA) -> block-sparse
// flash attention (bf16 MFMA, fp32 online softmax) -> out-proj GEMM (fp32 out).
// Workspace layout (requires 40 MB):
//   [0,8M)    hs_bf16  (reused as attn-out bf16 after QKV GEMM)
//   [8M,16M)  wq/wk/wv/wo bf16 (2 MB each)
//   [16M,40M) Q, K, V bf16 (8 MB each)
// ---------------------------------------------------------------------------

#define DEVI __device__ __forceinline__

typedef __bf16 bf16x8 __attribute__((ext_vector_type(8)));
typedef float floatx4 __attribute__((ext_vector_type(4)));
typedef unsigned short u16x8 __attribute__((ext_vector_type(8)));
typedef unsigned short u16x4 __attribute__((ext_vector_type(4)));
typedef unsigned int u32x4 __attribute__((ext_vector_type(4)));
typedef unsigned short ushort_t;

typedef const __attribute__((address_space(1))) void* gptr_as1;
typedef __attribute__((address_space(3))) void* lptr_as3;

DEVI ushort_t f2bf(float f) {  // round-to-nearest-even fp32 -> bf16
  unsigned u = __float_as_uint(f);
  unsigned r = ((u >> 16) & 1u) + 0x7fffu;
  return (ushort_t)((u + r) >> 16);
}

DEVI void lds_load16(void* lds, const void* g) {
  // async global->LDS, 16B/lane; LDS dest is wave-uniform base + lane*16
  __builtin_amdgcn_global_load_lds((gptr_as1)g, (lptr_as3)lds, 16, 0, 0);
}

DEVI floatx4 mfma16(bf16x8 a, bf16x8 b, floatx4 c) {
  return __builtin_amdgcn_mfma_f32_16x16x32_bf16(a, b, c, 0, 0, 0);
}

// ---------------------------------------------------------------------------
// Compile-time BigBird block mask: exact replication of numpy legacy
// RandomState(0) -> MT19937 init_genrand(0); choice(avail,3,replace=False) =
// permutation(n)[:3] = Fisher-Yates with random_interval(i) (32-bit masked
// rejection draws). Window |bi-bj|<=3, global row/col block 0.
// ---------------------------------------------------------------------------
struct MTState { unsigned mt[624]; int mti; };

constexpr unsigned mt_next(MTState& s) {
  if (s.mti >= 624) {
    for (int k = 0; k < 624; ++k) {
      unsigned y = (s.mt[k] & 0x80000000u) | (s.mt[(k + 1) % 624] & 0x7fffffffu);
      unsigned v = s.mt[(k + 397) % 624] ^ (y >> 1);
      if (y & 1u) v ^= 0x9908b0dfu;
      s.mt[k] = v;
    }
    s.mti = 0;
  }
  unsigned y = s.mt[s.mti++];
  y ^= y >> 11;
  y ^= (y << 7) & 0x9d2c5680u;
  y ^= (y << 15) & 0xefc60000u;
  y ^= y >> 18;
  return y;
}

constexpr unsigned mt_interval(MTState& s, unsigned mx) {  // uniform in [0,mx]
  if (mx == 0u) return 0u;
  unsigned msk = mx;
  msk |= msk >> 1; msk |= msk >> 2; msk |= msk >> 4; msk |= msk >> 8; msk |= msk >> 16;
  unsigned v = mt_next(s) & msk;
  while (v > mx) v = mt_next(s) & msk;
  return v;
}

struct MaskArr { unsigned char m[1024]; };

constexpr MaskArr make_mask() {
  MaskArr M{};
  for (int i = 0; i < 32; ++i)
    for (int j = 0; j < 32; ++j) {
      int d = i - j; if (d < 0) d = -d;
      M.m[i * 32 + j] = (i == 0 || j == 0 || d <= 3) ? (unsigned char)1 : (unsigned char)0;
    }
  MTState st{};
  st.mt[0] = 0u;
  for (int i = 1; i < 624; ++i)
    st.mt[i] = 1812433253u * (st.mt[i - 1] ^ (st.mt[i - 1] >> 30)) + (unsigned)i;
  st.mti = 624;
  for (int b = 1; b < 32; ++b) {
    int avail[32] = {}; int n = 0;
    for (int x = 1; x < 32; ++x) {
      int d = x - b; if (d < 0) d = -d;
      if (d > 3) avail[n++] = x;
    }
    if (n == 0) continue;
    int perm[32] = {};
    for (int i = 0; i < n; ++i) perm[i] = i;
    for (int i = n - 1; i > 0; --i) {
      unsigned j = mt_interval(st, (unsigned)i);
      int t = perm[i]; perm[i] = perm[(int)j]; perm[(int)j] = t;
    }
    int take = n < 3 ? n : 3;
    for (int s = 0; s < take; ++s) M.m[b * 32 + avail[perm[s]]] = 1;
  }
  return M;
}

__constant__ MaskArr MASK = make_mask();

// ---------------------------------------------------------------------------
// fp32 -> bf16 conversion, 4 elements/thread
// ---------------------------------------------------------------------------
__global__ void cvt_kernel(const float* __restrict__ src, ushort_t* __restrict__ dst, int n4) {
  int i = blockIdx.x * blockDim.x + threadIdx.x;
  if (i >= n4) return;
  const float4 f = ((const float4*)src)[i];
  u16x4 o;
  o.x = f2bf(f.x); o.y = f2bf(f.y); o.z = f2bf(f.z); o.w = f2bf(f.w);
  ((u16x4*)dst)[i] = o;
}

// ---------------------------------------------------------------------------
// C[m][n] = sum_k A[m][k]*W[n][k] + bias[n].  M=4096, N=K=1024.
// 128x128 tile, BK=32, 256 threads (4 waves, 2x2 of 64x64), 16x16x32 bf16 MFMA,
// global_load_lds width-16 staging (m97 structure).
// blockIdx.z selects one of up to 3 (W, bias, out) triples (fused QKV).
// ---------------------------------------------------------------------------
template <int OUT_BF16>
__global__ __launch_bounds__(256) void gemm_bt(
    const ushort_t* __restrict__ A,
    const ushort_t* __restrict__ W0, const ushort_t* __restrict__ W1, const ushort_t* __restrict__ W2,
    const float* __restrict__ b0, const float* __restrict__ b1, const float* __restrict__ b2,
    void* __restrict__ o0, void* __restrict__ o1, void* __restrict__ o2) {
  constexpr int N = 1024, K = 1024;
  __shared__ alignas(16) ushort_t As[128 * 32];
  __shared__ alignas(16) ushort_t Bs[128 * 32];
  const int z = blockIdx.z;
  const ushort_t* Bw = z == 0 ? W0 : (z == 1 ? W1 : W2);
  const float* bias = z == 0 ? b0 : (z == 1 ? b1 : b2);
  void* Cout = z == 0 ? o0 : (z == 1 ? o1 : o2);

  const int tid = threadIdx.x;
  const int w = tid >> 6, l = tid & 63, quad = l >> 4, li = l & 15;
  const int m0 = blockIdx.y * 128, n0 = blockIdx.x * 128;
  const int wm = (w >> 1) * 64, wn = (w & 1) * 64;

  // staging: chunk c covers LDS elements [(w*2+c)*512 + l*8, +8) (lane-contiguous)
  const int lof0 = (w * 2 + 0) * 512 + l * 8;
  const int lof1 = (w * 2 + 1) * 512 + l * 8;
  const int rA0 = lof0 >> 5, cA0 = lof0 & 31;
  const int rA1 = lof1 >> 5, cA1 = lof1 & 31;
  const ushort_t* gA0 = A + (size_t)(m0 + rA0) * K + cA0;
  const ushort_t* gA1 = A + (size_t)(m0 + rA1) * K + cA1;
  const ushort_t* gB0 = Bw + (size_t)(n0 + rA0) * K + cA0;
  const ushort_t* gB1 = Bw + (size_t)(n0 + rA1) * K + cA1;

  const floatx4 fzero = {0.0f, 0.0f, 0.0f, 0.0f};
  floatx4 acc[4][4];
#pragma unroll
  for (int i = 0; i < 4; ++i)
#pragma unroll
    for (int j = 0; j < 4; ++j) acc[i][j] = fzero;

  for (int k0 = 0; k0 < K; k0 += 32) {
    lds_load16(As + lof0, gA0 + k0);
    lds_load16(As + lof1, gA1 + k0);
    lds_load16(Bs + lof0, gB0 + k0);
    lds_load16(Bs + lof1, gB1 + k0);
    __syncthreads();
    bf16x8 af[4], bfr[4];
#pragma unroll
    for (int mi = 0; mi < 4; ++mi)
      af[mi] = *(const bf16x8*)(As + (wm + mi * 16 + li) * 32 + quad * 8);
#pragma unroll
    for (int ni = 0; ni < 4; ++ni)
      bfr[ni] = *(const bf16x8*)(Bs + (wn + ni * 16 + li) * 32 + quad * 8);
#pragma unroll
    for (int mi = 0; mi < 4; ++mi)
#pragma unroll
      for (int ni = 0; ni < 4; ++ni)
        acc[mi][ni] = mfma16(af[mi], bfr[ni], acc[mi][ni]);
    __syncthreads();
  }

  // epilogue: D[row=quad*4+r][col=li] per 16x16 tile (m89-verified C layout)
#pragma unroll
  for (int ni = 0; ni < 4; ++ni) {
    const int col = n0 + wn + ni * 16 + li;
    const float bv = bias[col];
#pragma unroll
    for (int mi = 0; mi < 4; ++mi) {
#pragma unroll
      for (int r = 0; r < 4; ++r) {
        const int row = m0 + wm + mi * 16 + quad * 4 + r;
        const float v = acc[mi][ni][r] + bv;
        if (OUT_BF16)
          ((ushort_t*)Cout)[(size_t)row * N + col] = f2bf(v);
        else
          ((float*)Cout)[(size_t)row * N + col] = v;
      }
    }
  }
}

// ---------------------------------------------------------------------------
// Block-sparse flash attention. Grid (qb=32, h=16, b=2), 256 threads.
// Wave w owns q-rows [qb*64+w*16, +16). Per active key block (64 keys):
// S = Q K^T * 0.125 (MFMA), online softmax (fp32), P->LDS, O += P V (MFMA).
// LDS strides padded (Ks/Ps: 72 el, Vs: 68 el) to de-conflict hot reads.
// ---------------------------------------------------------------------------
__global__ __launch_bounds__(256) void attn_kernel(
    const ushort_t* __restrict__ Q, const ushort_t* __restrict__ Kg,
    const ushort_t* __restrict__ Vg, ushort_t* __restrict__ O) {
  constexpr int E = 1024;
  __shared__ alignas(16) ushort_t Ks[64 * 72];
  __shared__ alignas(16) ushort_t Vs[64 * 68];
  __shared__ alignas(16) ushort_t Ps[4][16 * 72];

  const int tid = threadIdx.x;
  const int w = tid >> 6, l = tid & 63, quad = l >> 4, li = l & 15;
  const int qb = blockIdx.x, h = blockIdx.y, b = blockIdx.z;
  const size_t headoff = (size_t)b * 2048 * E + (size_t)h * 64;

  // Q fragments (A-layout: m=li, k=quad*8+j), kept in registers
  const int qrow = qb * 64 + w * 16 + li;
  const bf16x8 aq0 = *(const bf16x8*)(Q + headoff + (size_t)qrow * E + quad * 8);
  const bf16x8 aq1 = *(const bf16x8*)(Q + headoff + (size_t)qrow * E + 32 + quad * 8);

  const floatx4 fzero = {0.0f, 0.0f, 0.0f, 0.0f};
  float m_i[4], l_i[4];
  floatx4 o_acc[4];
#pragma unroll
  for (int r = 0; r < 4; ++r) { m_i[r] = -__builtin_inff(); l_i[r] = 0.0f; }
#pragma unroll
  for (int nt = 0; nt < 4; ++nt) o_acc[nt] = fzero;

  const unsigned char* mrow = MASK.m + qb * 32;
  for (int kb = 0; kb < 32; ++kb) {
    if (!mrow[kb]) continue;  // uniform branch (scalar)
    const size_t kvbase = headoff + (size_t)kb * 64 * E;
    // stage K (stride 72) and V (stride 68): 2 x 16B per thread each
#pragma unroll
    for (int c = 0; c < 2; ++c) {
      const int row = (w * 2 + c) * 8 + (l >> 3);
      const int col = (l & 7) * 8;
      const u16x8 kv = *(const u16x8*)(Kg + kvbase + (size_t)row * E + col);
      *(u16x8*)(Ks + row * 72 + col) = kv;
      const u16x8 vv = *(const u16x8*)(Vg + kvbase + (size_t)row * E + col);
      *(u16x4*)(Vs + row * 68 + col) = vv.lo;
      *(u16x4*)(Vs + row * 68 + col + 4) = vv.hi;
    }
    __syncthreads();

    // S = Q K^T (B-layout: n=li -> K row nt*16+li, contiguous in D)
    floatx4 s[4];
#pragma unroll
    for (int nt = 0; nt < 4; ++nt) {
      const bf16x8 bk0 = *(const bf16x8*)(Ks + (nt * 16 + li) * 72 + quad * 8);
      const bf16x8 bk1 = *(const bf16x8*)(Ks + (nt * 16 + li) * 72 + 32 + quad * 8);
      floatx4 zz = fzero;
      zz = mfma16(aq0, bk0, zz);
      zz = mfma16(aq1, bk1, zz);
      s[nt] = zz;
    }
#pragma unroll
    for (int nt = 0; nt < 4; ++nt)
#pragma unroll
      for (int r = 0; r < 4; ++r) s[nt][r] *= 0.125f;

    // online softmax; row quad*4+r lives across the quad's 16 lanes
#pragma unroll
    for (int r = 0; r < 4; ++r) {
      float t = fmaxf(fmaxf(s[0][r], s[1][r]), fmaxf(s[2][r], s[3][r]));
      t = fmaxf(t, __shfl_xor(t, 1));
      t = fmaxf(t, __shfl_xor(t, 2));
      t = fmaxf(t, __shfl_xor(t, 4));
      t = fmaxf(t, __shfl_xor(t, 8));
      const float mnew = fmaxf(m_i[r], t);
      const float alpha = __expf(m_i[r] - mnew);  // exp(-inf)=0 first time
      m_i[r] = mnew;
      float rs = 0.0f;
#pragma unroll
      for (int nt = 0; nt < 4; ++nt) {
        const float p = __expf(s[nt][r] - mnew);
        s[nt][r] = p;
        rs += p;
      }
      rs += __shfl_xor(rs, 1);
      rs += __shfl_xor(rs, 2);
      rs += __shfl_xor(rs, 4);
      rs += __shfl_xor(rs, 8);
      l_i[r] = l_i[r] * alpha + rs;
#pragma unroll
      for (int nt = 0; nt < 4; ++nt) o_acc[nt][r] *= alpha;
    }

    // P (C-layout) -> LDS for A-layout re-read
#pragma unroll
    for (int nt = 0; nt < 4; ++nt)
#pragma unroll
      for (int r = 0; r < 4; ++r)
        Ps[w][(quad * 4 + r) * 72 + nt * 16 + li] = f2bf(s[nt][r]);
    __syncthreads();

    // O += P V  (V^T fragment gathered with scalar LDS reads; round-1 cost)
#pragma unroll
    for (int c = 0; c < 2; ++c) {
      const bf16x8 pa = *(const bf16x8*)(Ps[w] + li * 72 + c * 32 + quad * 8);
#pragma unroll
      for (int nt = 0; nt < 4; ++nt) {
        u32x4 pk;
#pragma unroll
        for (int jj = 0; jj < 4; ++jj) {
          const unsigned lo = Vs[(c * 32 + quad * 8 + 2 * jj) * 68 + nt * 16 + li];
          const unsigned hi = Vs[(c * 32 + quad * 8 + 2 * jj + 1) * 68 + nt * 16 + li];
          pk[jj] = lo | (hi << 16);
        }
        const bf16x8 vb = __builtin_bit_cast(bf16x8, pk);
        o_acc[nt] = mfma16(pa, vb, o_acc[nt]);
      }
    }
    __syncthreads();
  }

  // epilogue: O[b][s][h*64+d] bf16
#pragma unroll
  for (int nt = 0; nt < 4; ++nt)
#pragma unroll
    for (int r = 0; r < 4; ++r) {
      const float ov = o_acc[nt][r] / l_i[r];
      O[headoff + (size_t)(qb * 64 + w * 16 + quad * 4 + r) * E + nt * 16 + li] = f2bf(ov);
    }
}

// ---------------------------------------------------------------------------
extern "C" void kernel_launch(void* const* d_in, const int* in_sizes, int n_in,
                              void* d_out, int out_size, void* d_ws, size_t ws_size,
                              hipStream_t stream) {
  const float* hs = (const float*)d_in[0];
  const float* wq = (const float*)d_in[1];
  const float* bq = (const float*)d_in[2];
  const float* wk = (const float*)d_in[3];
  const float* bk = (const float*)d_in[4];
  const float* wv = (const float*)d_in[5];
  const float* bv = (const float*)d_in[6];
  const float* wo = (const float*)d_in[7];
  const float* bo = (const float*)d_in[8];
  float* out = (float*)d_out;

  char* ws = (char*)d_ws;
  ushort_t* hs_bf = (ushort_t*)(ws);                       // 8 MB
  ushort_t* wq_bf = (ushort_t*)(ws + (8ull << 20));        // 2 MB
  ushort_t* wk_bf = (ushort_t*)(ws + (10ull << 20));
  ushort_t* wv_bf = (ushort_t*)(ws + (12ull << 20));
  ushort_t* wo_bf = (ushort_t*)(ws + (14ull << 20));
  ushort_t* Qb = (ushort_t*)(ws + (16ull << 20));          // 8 MB each
  ushort_t* Kb = (ushort_t*)(ws + (24ull << 20));
  ushort_t* Vb = (ushort_t*)(ws + (32ull << 20));
  ushort_t* AO = hs_bf;  // hs_bf dead after QKV GEMM; reuse for attn output

  cvt_kernel<<<4096, 256, 0, stream>>>(hs, hs_bf, 1048576);
  cvt_kernel<<<1024, 256, 0, stream>>>(wq, wq_bf, 262144);
  cvt_kernel<<<1024, 256, 0, stream>>>(wk, wk_bf, 262144);
  cvt_kernel<<<1024, 256, 0, stream>>>(wv, wv_bf, 262144);
  cvt_kernel<<<1024, 256, 0, stream>>>(wo, wo_bf, 262144);

  dim3 gq(8, 32, 3);  // fused Q,K,V projections
  gemm_bt<1><<<gq, 256, 0, stream>>>(hs_bf, wq_bf, wk_bf, wv_bf, bq, bk, bv, Qb, Kb, Vb);

  dim3 ga(32, 16, 2);
  attn_kernel<<<ga, 256, 0, stream>>>(Qb, Kb, Vb, AO);

  dim3 go(8, 32, 1);
  gemm_bt<0><<<go, 256, 0, stream>>>(AO, wo_bf, wo_bf, wo_bf, bo, bo, bo, out, out, out);
}

// Round 2
// 264.425 us; speedup vs baseline: 1.1102x; 1.1102x over previous
//
#include <hip/hip_runtime.h>
#include <cstdint>
#include <math.h>

// ---------------------------------------------------------------------------
// BigBird attention, MI355X. B=2, S=2048, E=1024, H=16, D=64, BLOCK=64, NB=32.
// Pipeline: fused fp32->bf16 cvt -> fused QKV GEMM (bf16 MFMA) -> V transpose
// -> block-sparse flash attention (bf16 MFMA, fp32 online softmax, register
// prefetch of next K/Vt block across barriers) -> out-proj GEMM (fp32 out).
// Workspace layout (40 MB):
//   [0,8M)    hs_bf16      -> reused as Vt (64 x 2048 per (b,h)) after QKV GEMM
//   [8M,16M)  wq/wk/wv/wo bf16 (2 MB each)
//   [16M,32M) Q, K bf16 (8 MB each)
//   [32M,40M) V bf16       -> reused as attn-out bf16 after V transpose
// ---------------------------------------------------------------------------

#define DEVI __device__ __forceinline__

typedef __bf16 bf16x8 __attribute__((ext_vector_type(8)));
typedef float floatx4 __attribute__((ext_vector_type(4)));
typedef unsigned short u16x8 __attribute__((ext_vector_type(8)));
typedef unsigned short u16x4 __attribute__((ext_vector_type(4)));
typedef unsigned short ushort_t;

typedef const __attribute__((address_space(1))) void* gptr_as1;
typedef __attribute__((address_space(3))) void* lptr_as3;

DEVI ushort_t f2bf(float f) {  // round-to-nearest-even fp32 -> bf16
  unsigned u = __float_as_uint(f);
  unsigned r = ((u >> 16) & 1u) + 0x7fffu;
  return (ushort_t)((u + r) >> 16);
}

DEVI void lds_load16(void* lds, const void* g) {
  __builtin_amdgcn_global_load_lds((gptr_as1)g, (lptr_as3)lds, 16, 0, 0);
}

DEVI floatx4 mfma16(bf16x8 a, bf16x8 b, floatx4 c) {
  return __builtin_amdgcn_mfma_f32_16x16x32_bf16(a, b, c, 0, 0, 0);
}

// ---------------------------------------------------------------------------
// Compile-time BigBird block mask (exact numpy legacy RandomState(0) MT19937
// replication — verified vs reference in round 1). Compacted to per-row
// active-block lists so the attention loop has no wasted iterations.
// ---------------------------------------------------------------------------
struct MTState { unsigned mt[624]; int mti; };

constexpr unsigned mt_next(MTState& s) {
  if (s.mti >= 624) {
    for (int k = 0; k < 624; ++k) {
      unsigned y = (s.mt[k] & 0x80000000u) | (s.mt[(k + 1) % 624] & 0x7fffffffu);
      unsigned v = s.mt[(k + 397) % 624] ^ (y >> 1);
      if (y & 1u) v ^= 0x9908b0dfu;
      s.mt[k] = v;
    }
    s.mti = 0;
  }
  unsigned y = s.mt[s.mti++];
  y ^= y >> 11;
  y ^= (y << 7) & 0x9d2c5680u;
  y ^= (y << 15) & 0xefc60000u;
  y ^= y >> 18;
  return y;
}

constexpr unsigned mt_interval(MTState& s, unsigned mx) {  // uniform in [0,mx]
  if (mx == 0u) return 0u;
  unsigned msk = mx;
  msk |= msk >> 1; msk |= msk >> 2; msk |= msk >> 4; msk |= msk >> 8; msk |= msk >> 16;
  unsigned v = mt_next(s) & msk;
  while (v > mx) v = mt_next(s) & msk;
  return v;
}

struct MaskPack { unsigned char list[32][32]; int cnt[32]; };

constexpr MaskPack make_pack() {
  unsigned char m[32][32] = {};
  for (int i = 0; i < 32; ++i)
    for (int j = 0; j < 32; ++j) {
      int d = i - j; if (d < 0) d = -d;
      m[i][j] = (i == 0 || j == 0 || d <= 3) ? (unsigned char)1 : (unsigned char)0;
    }
  MTState st{};
  st.mt[0] = 0u;
  for (int i = 1; i < 624; ++i)
    st.mt[i] = 1812433253u * (st.mt[i - 1] ^ (st.mt[i - 1] >> 30)) + (unsigned)i;
  st.mti = 624;
  for (int b = 1; b < 32; ++b) {
    int avail[32] = {}; int n = 0;
    for (int x = 1; x < 32; ++x) {
      int d = x - b; if (d < 0) d = -d;
      if (d > 3) avail[n++] = x;
    }
    if (n == 0) continue;
    int perm[32] = {};
    for (int i = 0; i < n; ++i) perm[i] = i;
    for (int i = n - 1; i > 0; --i) {
      unsigned j = mt_interval(st, (unsigned)i);
      int t = perm[i]; perm[i] = perm[(int)j]; perm[(int)j] = t;
    }
    int take = n < 3 ? n : 3;
    for (int s = 0; s < take; ++s) m[b][avail[perm[s]]] = 1;
  }
  MaskPack P{};
  for (int i = 0; i < 32; ++i) {
    int c = 0;
    for (int j = 0; j < 32; ++j)
      if (m[i][j]) P.list[i][c++] = (unsigned char)j;
    P.cnt[i] = c;
  }
  return P;
}

__constant__ MaskPack MP = make_pack();

// ---------------------------------------------------------------------------
// Fused fp32 -> bf16 conversion for hs + 4 weight matrices, 4 el/thread.
// Flat index space: [0,1048576) -> hs; then 4 x 262144 (=2^18) -> wq,wk,wv,wo.
// ---------------------------------------------------------------------------
__global__ __launch_bounds__(256) void cvt_all(
    const float* __restrict__ hs, const float* __restrict__ wq,
    const float* __restrict__ wk, const float* __restrict__ wv,
    const float* __restrict__ wo,
    ushort_t* __restrict__ hs_bf, ushort_t* __restrict__ wq_bf,
    ushort_t* __restrict__ wk_bf, ushort_t* __restrict__ wv_bf,
    ushort_t* __restrict__ wo_bf) {
  const int i = blockIdx.x * 256 + threadIdx.x;
  const float* s;
  ushort_t* d;
  int j;
  if (i < 1048576) {
    s = hs; d = hs_bf; j = i;
  } else {
    const int t = (i - 1048576) >> 18;
    j = (i - 1048576) & 262143;
    s = t == 0 ? wq : (t == 1 ? wk : (t == 2 ? wv : wo));
    d = t == 0 ? wq_bf : (t == 1 ? wk_bf : (t == 2 ? wv_bf : wo_bf));
  }
  const float4 f = ((const float4*)s)[j];
  u16x4 o;
  o.x = f2bf(f.x); o.y = f2bf(f.y); o.z = f2bf(f.z); o.w = f2bf(f.w);
  ((u16x4*)d)[j] = o;
}

// ---------------------------------------------------------------------------
// C[m][n] = sum_k A[m][k]*W[n][k] + bias[n].  M=4096, N=K=1024.
// 128x128 tile, BK=32, 256 threads, 16x16x32 bf16 MFMA, global_load_lds
// width-16 staging (m97 structure). blockIdx.z selects (W, bias, out) triple.
// ---------------------------------------------------------------------------
template <int OUT_BF16>
__global__ __launch_bounds__(256) void gemm_bt(
    const ushort_t* __restrict__ A,
    const ushort_t* __restrict__ W0, const ushort_t* __restrict__ W1, const ushort_t* __restrict__ W2,
    const float* __restrict__ b0, const float* __restrict__ b1, const float* __restrict__ b2,
    void* __restrict__ o0, void* __restrict__ o1, void* __restrict__ o2) {
  constexpr int N = 1024, K = 1024;
  __shared__ alignas(16) ushort_t As[128 * 32];
  __shared__ alignas(16) ushort_t Bs[128 * 32];
  const int z = blockIdx.z;
  const ushort_t* Bw = z == 0 ? W0 : (z == 1 ? W1 : W2);
  const float* bias = z == 0 ? b0 : (z == 1 ? b1 : b2);
  void* Cout = z == 0 ? o0 : (z == 1 ? o1 : o2);

  const int tid = threadIdx.x;
  const int w = tid >> 6, l = tid & 63, quad = l >> 4, li = l & 15;
  const int m0 = blockIdx.y * 128, n0 = blockIdx.x * 128;
  const int wm = (w >> 1) * 64, wn = (w & 1) * 64;

  const int lof0 = (w * 2 + 0) * 512 + l * 8;
  const int lof1 = (w * 2 + 1) * 512 + l * 8;
  const int rA0 = lof0 >> 5, cA0 = lof0 & 31;
  const int rA1 = lof1 >> 5, cA1 = lof1 & 31;
  const ushort_t* gA0 = A + (size_t)(m0 + rA0) * K + cA0;
  const ushort_t* gA1 = A + (size_t)(m0 + rA1) * K + cA1;
  const ushort_t* gB0 = Bw + (size_t)(n0 + rA0) * K + cA0;
  const ushort_t* gB1 = Bw + (size_t)(n0 + rA1) * K + cA1;

  const floatx4 fzero = {0.0f, 0.0f, 0.0f, 0.0f};
  floatx4 acc[4][4];
#pragma unroll
  for (int i = 0; i < 4; ++i)
#pragma unroll
    for (int j = 0; j < 4; ++j) acc[i][j] = fzero;

  for (int k0 = 0; k0 < K; k0 += 32) {
    lds_load16(As + lof0, gA0 + k0);
    lds_load16(As + lof1, gA1 + k0);
    lds_load16(Bs + lof0, gB0 + k0);
    lds_load16(Bs + lof1, gB1 + k0);
    __syncthreads();
    bf16x8 af[4], bfr[4];
#pragma unroll
    for (int mi = 0; mi < 4; ++mi)
      af[mi] = *(const bf16x8*)(As + (wm + mi * 16 + li) * 32 + quad * 8);
#pragma unroll
    for (int ni = 0; ni < 4; ++ni)
      bfr[ni] = *(const bf16x8*)(Bs + (wn + ni * 16 + li) * 32 + quad * 8);
#pragma unroll
    for (int mi = 0; mi < 4; ++mi)
#pragma unroll
      for (int ni = 0; ni < 4; ++ni)
        acc[mi][ni] = mfma16(af[mi], bfr[ni], acc[mi][ni]);
    __syncthreads();
  }

#pragma unroll
  for (int ni = 0; ni < 4; ++ni) {
    const int col = n0 + wn + ni * 16 + li;
    const float bv = bias[col];
#pragma unroll
    for (int mi = 0; mi < 4; ++mi) {
#pragma unroll
      for (int r = 0; r < 4; ++r) {
        const int row = m0 + wm + mi * 16 + quad * 4 + r;
        const float v = acc[mi][ni][r] + bv;
        if (OUT_BF16)
          ((ushort_t*)Cout)[(size_t)row * N + col] = f2bf(v);
        else
          ((float*)Cout)[(size_t)row * N + col] = v;
      }
    }
  }
}

// ---------------------------------------------------------------------------
// V transpose: V[b*2048+s][h*64+d] -> Vt[(b*16+h)*64+d][s].  64x64 LDS tiles.
// Makes the attention PV B-fragment a contiguous ds_read_b128.
// ---------------------------------------------------------------------------
__global__ __launch_bounds__(256) void vtrans_kernel(
    const ushort_t* __restrict__ V, ushort_t* __restrict__ Vt) {
  __shared__ alignas(16) ushort_t T[64 * 72];
  const int tid = threadIdx.x;
  const int s0 = blockIdx.x * 64, h = blockIdx.y, b = blockIdx.z;
  const int r = tid >> 2, cg = tid & 3;
  const ushort_t* src = V + (size_t)(b * 2048 + s0 + r) * 1024 + h * 64 + cg * 16;
  *(u16x8*)(T + r * 72 + cg * 16) = *(const u16x8*)src;
  *(u16x8*)(T + r * 72 + cg * 16 + 8) = *(const u16x8*)(src + 8);
  __syncthreads();
  u16x8 a0, a1;
#pragma unroll
  for (int j = 0; j < 8; ++j) a0[j] = T[(cg * 16 + j) * 72 + r];
#pragma unroll
  for (int j = 0; j < 8; ++j) a1[j] = T[(cg * 16 + 8 + j) * 72 + r];
  ushort_t* dst = Vt + (size_t)((b * 16 + h) * 64 + r) * 2048 + s0 + cg * 16;
  *(u16x8*)dst = a0;
  *(u16x8*)(dst + 8) = a1;
}

// ---------------------------------------------------------------------------
// Block-sparse flash attention. Grid (qb=32, h=16, b=2), 256 threads.
// Wave w owns q-rows [qb*64+w*16, +16). Per active key block:
//   S = (Q/8) K^T (MFMA), online softmax (fp32), P->LDS (per-wave, no
//   barrier), O += P V (MFMA, contiguous Vt fragments).
// Next block's K/Vt prefetched into registers across the barriers (plain
// global->VGPR loads stay in flight across s_barrier; the ds_write of the
// prefetch regs is where vmcnt waits land).
// ---------------------------------------------------------------------------
__global__ __launch_bounds__(256) void attn_kernel(
    const ushort_t* __restrict__ Q, const ushort_t* __restrict__ Kg,
    const ushort_t* __restrict__ Vtg, ushort_t* __restrict__ O) {
  __shared__ alignas(16) ushort_t Ks[64 * 72];
  __shared__ alignas(16) ushort_t Vts[64 * 72];
  __shared__ alignas(16) ushort_t Ps[4][16 * 72];

  const int tid = threadIdx.x;
  const int w = tid >> 6, l = tid & 63, quad = l >> 4, li = l & 15;
  const int qb = blockIdx.x, h = blockIdx.y, b = blockIdx.z;
  const size_t qoff = (size_t)b * 2048 * 1024 + (size_t)h * 64;
  const size_t vtoff = (size_t)(b * 16 + h) * 64 * 2048;

  const int rowS = tid >> 2, colS = (tid & 3) * 16;

  // Q fragments (A-layout), pre-scaled by 2^-3 (exact in bf16)
  const int qrow = qb * 64 + w * 16 + li;
  bf16x8 aq0 = *(const bf16x8*)(Q + qoff + (size_t)qrow * 1024 + quad * 8);
  bf16x8 aq1 = *(const bf16x8*)(Q + qoff + (size_t)qrow * 1024 + 32 + quad * 8);
#pragma unroll
  for (int j = 0; j < 8; ++j) {
    aq0[j] = (__bf16)((float)aq0[j] * 0.125f);
    aq1[j] = (__bf16)((float)aq1[j] * 0.125f);
  }

  const floatx4 fzero = {0.0f, 0.0f, 0.0f, 0.0f};
  float m_i[4], l_i[4];
  floatx4 o_acc[4];
#pragma unroll
  for (int r = 0; r < 4; ++r) { m_i[r] = -__builtin_inff(); l_i[r] = 0.0f; }
#pragma unroll
  for (int nt = 0; nt < 4; ++nt) o_acc[nt] = fzero;

  const int nact = MP.cnt[qb];
  int kb = MP.list[qb][0];
  const ushort_t* kp = Kg + qoff + (size_t)(kb * 64 + rowS) * 1024 + colS;
  const ushort_t* vp = Vtg + vtoff + (size_t)rowS * 2048 + kb * 64 + colS;
  u16x8 pk0 = *(const u16x8*)kp;
  u16x8 pk1 = *(const u16x8*)(kp + 8);
  u16x8 pv0 = *(const u16x8*)vp;
  u16x8 pv1 = *(const u16x8*)(vp + 8);

  for (int i = 0; i < nact; ++i) {
    __syncthreads();  // previous iteration done reading Ks/Vts
    *(u16x8*)(Ks + rowS * 72 + colS) = pk0;
    *(u16x8*)(Ks + rowS * 72 + colS + 8) = pk1;
    *(u16x8*)(Vts + rowS * 72 + colS) = pv0;
    *(u16x8*)(Vts + rowS * 72 + colS + 8) = pv1;
    __syncthreads();
    if (i + 1 < nact) {  // uniform branch; loads overlap the compute below
      kb = MP.list[qb][i + 1];
      kp = Kg + qoff + (size_t)(kb * 64 + rowS) * 1024 + colS;
      vp = Vtg + vtoff + (size_t)rowS * 2048 + kb * 64 + colS;
      pk0 = *(const u16x8*)kp;
      pk1 = *(const u16x8*)(kp + 8);
      pv0 = *(const u16x8*)vp;
      pv1 = *(const u16x8*)(vp + 8);
    }

    // S = (Q/8) K^T  (B-frag: n=li -> K row nt*16+li, contiguous in D)
    floatx4 s[4];
#pragma unroll
    for (int nt = 0; nt < 4; ++nt) {
      const bf16x8 bk0 = *(const bf16x8*)(Ks + (nt * 16 + li) * 72 + quad * 8);
      const bf16x8 bk1 = *(const bf16x8*)(Ks + (nt * 16 + li) * 72 + 32 + quad * 8);
      s[nt] = mfma16(aq1, bk1, mfma16(aq0, bk0, fzero));
    }

    // online softmax — phased so the 4 rows' shuffle chains interleave
    float mx[4];
#pragma unroll
    for (int r = 0; r < 4; ++r)
      mx[r] = fmaxf(fmaxf(s[0][r], s[1][r]), fmaxf(s[2][r], s[3][r]));
#pragma unroll
    for (int st = 1; st <= 8; st <<= 1)
#pragma unroll
      for (int r = 0; r < 4; ++r) mx[r] = fmaxf(mx[r], __shfl_xor(mx[r], st));
    float alpha[4];
#pragma unroll
    for (int r = 0; r < 4; ++r) {
      const float mnew = fmaxf(m_i[r], mx[r]);
      alpha[r] = __expf(m_i[r] - mnew);  // exp(-inf)=0 first time
      m_i[r] = mnew;
    }
    float rs[4];
#pragma unroll
    for (int r = 0; r < 4; ++r) {
      float acc_p = 0.0f;
#pragma unroll
      for (int nt = 0; nt < 4; ++nt) {
        const float p = __expf(s[nt][r] - m_i[r]);
        s[nt][r] = p;
        acc_p += p;
      }
      rs[r] = acc_p;
    }
#pragma unroll
    for (int st = 1; st <= 8; st <<= 1)
#pragma unroll
      for (int r = 0; r < 4; ++r) rs[r] += __shfl_xor(rs[r], st);
#pragma unroll
    for (int r = 0; r < 4; ++r) {
      l_i[r] = l_i[r] * alpha[r] + rs[r];
#pragma unroll
      for (int nt = 0; nt < 4; ++nt) o_acc[nt][r] *= alpha[r];
    }

    // P (C-layout) -> per-wave LDS -> A-layout (in-order DS pipe, no barrier)
#pragma unroll
    for (int nt = 0; nt < 4; ++nt)
#pragma unroll
      for (int r = 0; r < 4; ++r)
        Ps[w][(quad * 4 + r) * 72 + nt * 16 + li] = f2bf(s[nt][r]);

    // O += P V   (B-frag from Vt: contiguous ds_read_b128)
#pragma unroll
    for (int c = 0; c < 2; ++c) {
      const bf16x8 pa = *(const bf16x8*)(Ps[w] + li * 72 + c * 32 + quad * 8);
#pragma unroll
      for (int nt = 0; nt < 4; ++nt) {
        const bf16x8 vb = *(const bf16x8*)(Vts + (nt * 16 + li) * 72 + c * 32 + quad * 8);
        o_acc[nt] = mfma16(pa, vb, o_acc[nt]);
      }
    }
  }

  // epilogue: O[b][s][h*64+d] bf16
#pragma unroll
  for (int r = 0; r < 4; ++r) {
    const float rinv = 1.0f / l_i[r];
#pragma unroll
    for (int nt = 0; nt < 4; ++nt) {
      const float ov = o_acc[nt][r] * rinv;
      O[qoff + (size_t)(qb * 64 + w * 16 + quad * 4 + r) * 1024 + nt * 16 + li] = f2bf(ov);
    }
  }
}

// ---------------------------------------------------------------------------
extern "C" void kernel_launch(void* const* d_in, const int* in_sizes, int n_in,
                              void* d_out, int out_size, void* d_ws, size_t ws_size,
                              hipStream_t stream) {
  const float* hs = (const float*)d_in[0];
  const float* wq = (const float*)d_in[1];
  const float* bq = (const float*)d_in[2];
  const float* wk = (const float*)d_in[3];
  const float* bk = (const float*)d_in[4];
  const float* wv = (const float*)d_in[5];
  const float* bv = (const float*)d_in[6];
  const float* wo = (const float*)d_in[7];
  const float* bo = (const float*)d_in[8];
  float* out = (float*)d_out;

  char* ws = (char*)d_ws;
  ushort_t* hs_bf = (ushort_t*)(ws);                 // 8 MB; reused as Vt
  ushort_t* wq_bf = (ushort_t*)(ws + (8ull << 20));  // 2 MB each
  ushort_t* wk_bf = (ushort_t*)(ws + (10ull << 20));
  ushort_t* wv_bf = (ushort_t*)(ws + (12ull << 20));
  ushort_t* wo_bf = (ushort_t*)(ws + (14ull << 20));
  ushort_t* Qb = (ushort_t*)(ws + (16ull << 20));    // 8 MB each
  ushort_t* Kb = (ushort_t*)(ws + (24ull << 20));
  ushort_t* Vb = (ushort_t*)(ws + (32ull << 20));
  ushort_t* Vt = hs_bf;  // hs_bf dead after QKV GEMM
  ushort_t* AO = Vb;     // V raw dead after transpose

  cvt_all<<<8192, 256, 0, stream>>>(hs, wq, wk, wv, wo,
                                    hs_bf, wq_bf, wk_bf, wv_bf, wo_bf);

  dim3 gq(8, 32, 3);  // fused Q,K,V projections
  gemm_bt<1><<<gq, 256, 0, stream>>>(hs_bf, wq_bf, wk_bf, wv_bf, bq, bk, bv, Qb, Kb, Vb);

  dim3 gt(32, 16, 2);
  vtrans_kernel<<<gt, 256, 0, stream>>>(Vb, Vt);

  dim3 ga(32, 16, 2);
  attn_kernel<<<ga, 256, 0, stream>>>(Qb, Kb, Vt, AO);

  dim3 go(8, 32, 1);
  gemm_bt<0><<<go, 256, 0, stream>>>(AO, wo_bf, wo_bf, wo_bf, bo, bo, bo, out, out, out);
}